// Round 1
// 94.194 us; speedup vs baseline: 1.0297x; 1.0297x over previous
//
#include <hip/hip_runtime.h>

// ColorReducer: per pixel argmin_k ||p - palette[k]||^2, output palette color,
// planar (B,3,H,W) layout.
//
// CORRECTNESS CONTRACT (R4, carried forward): ref=np is numpy fp32. numpy's
// c_einsum SOP remainder loop contracts to an ascending scalar FMA chain:
//   dot = fma(b,cb, fma(g,cg, rn(r*cr)))     <- acc=0, ascending
// np.sum(pix*pix) / np.sum(pal*pal) are separate ufunc passes (no FMA),
// pairwise base case n<8 = forward:
//   pp = ((r*r + g*g) + b*b),  cc = ((cr*cr + cg*cg) + cb*cb)
// d = (pp - 2*dot) + cc  left-to-right; argmin first-index strict <.
//
// R5 TRANSFORM (bit-exact): precompute per-color (-2cr,-2cg,-2cb). Since RNE
// rounding commutes with exact power-of-2 scaling and negation (and no
// denormals can occur: inputs are multiples of 2^-23, every product >= 2^-46),
//   fma(b,-2cb, fma(g,-2cg, rn(r*(-2cr)))) == -2*dot   bit-exactly, and
//   d = rn(rn(pp + nd2) + cc) == rn(rn(pp - 2*dot) + cc).
// This deletes the per-color doubling add: 9 -> 8 VALU ops/color.
// Original palette values kept in a second LDS array for the output gather.

constexpr int HW   = 512 * 512;   // pixels per plane (2^18)
constexpr int NCOL = 64;

__global__ __launch_bounds__(256)
void color_reduce_kernel(const float* __restrict__ x,
                         const float* __restrict__ pal,
                         float* __restrict__ out,
                         int npix4) {
  __shared__ float4 coefN[NCOL];  // (-2cr, -2cg, -2cb, cc)
  __shared__ float4 palf[NCOL];   // (cr, cg, cb, --) original colors for output
  const int tid = threadIdx.x;
  if (tid < NCOL) {
    const float cr = pal[tid * 3 + 0];
    const float cg = pal[tid * 3 + 1];
    const float cb = pal[tid * 3 + 2];
    const float cc = __fadd_rn(__fadd_rn(__fmul_rn(cr, cr), __fmul_rn(cg, cg)),
                               __fmul_rn(cb, cb));
    coefN[tid] = make_float4(__fmul_rn(-2.0f, cr),
                             __fmul_rn(-2.0f, cg),
                             __fmul_rn(-2.0f, cb), cc);
    palf[tid] = make_float4(cr, cg, cb, 0.0f);
  }
  __syncthreads();

  const int i4 = blockIdx.x * blockDim.x + tid;   // group of 4 consecutive pixels
  if (i4 >= npix4) return;
  const int pix = i4 << 2;
  const int b   = pix >> 18;        // / HW
  const int j   = pix & (HW - 1);   // % HW
  const size_t base = (size_t)b * (3 * HW) + j;

  const float4 R  = *(const float4*)(x + base);
  const float4 G  = *(const float4*)(x + base + HW);
  const float4 Bl = *(const float4*)(x + base + 2 * HW);
  const float rr[4] = {R.x, R.y, R.z, R.w};
  const float gg[4] = {G.x, G.y, G.z, G.w};
  const float bb[4] = {Bl.x, Bl.y, Bl.z, Bl.w};

  float pp[4], m1[4];
  int idx[4];
#pragma unroll
  for (int p = 0; p < 4; ++p) {
    pp[p] = __fadd_rn(__fadd_rn(__fmul_rn(rr[p], rr[p]), __fmul_rn(gg[p], gg[p])),
                      __fmul_rn(bb[p], bb[p]));
    m1[p] = 3.4e38f;
    idx[p] = 0;
  }

  // Full unroll: k becomes an inline constant (0..63 are free inline consts)
  // in the idx cndmask; coef reads become ds_read_b128 with imm offsets.
#pragma unroll
  for (int k = 0; k < NCOL; ++k) {
    const float4 cf = coefN[k];
#pragma unroll
    for (int p = 0; p < 4; ++p) {
      // nd2 == -2*dot bit-exactly (see header comment)
      const float nd2 = __fmaf_rn(bb[p], cf.z,
                          __fmaf_rn(gg[p], cf.y,
                            __fmul_rn(rr[p], cf.x)));
      const float d = __fadd_rn(__fadd_rn(pp[p], nd2), cf.w);
      const bool lt = d < m1[p];                 // strict < => first-index tie-break
      m1[p]  = lt ? d : m1[p];
      idx[p] = lt ? k : idx[p];
    }
  }

  const float4 c0 = palf[idx[0]], c1 = palf[idx[1]],
               c2 = palf[idx[2]], c3 = palf[idx[3]];
  *(float4*)(out + base)          = make_float4(c0.x, c1.x, c2.x, c3.x);
  *(float4*)(out + base + HW)     = make_float4(c0.y, c1.y, c2.y, c3.y);
  *(float4*)(out + base + 2 * HW) = make_float4(c0.z, c1.z, c2.z, c3.z);
}

extern "C" void kernel_launch(void* const* d_in, const int* in_sizes, int n_in,
                              void* d_out, int out_size, void* d_ws, size_t ws_size,
                              hipStream_t stream) {
  const float* x   = (const float*)d_in[0];
  const float* pal = (const float*)d_in[1];
  float* out = (float*)d_out;

  const int npix  = in_sizes[0] / 3;   // B*H*W = 2,097,152
  const int npix4 = npix / 4;          // 524,288 threads
  const int block = 256;
  const int grid  = (npix4 + block - 1) / block;
  hipLaunchKernelGGL(color_reduce_kernel, dim3(grid), dim3(block), 0, stream,
                     x, pal, out, npix4);
}

// Round 2
// 93.811 us; speedup vs baseline: 1.0339x; 1.0041x over previous
//
#include <hip/hip_runtime.h>

// ColorReducer: per pixel argmin_k ||p - palette[k]||^2, output palette color,
// planar (B,3,H,W) layout.
//
// CORRECTNESS CONTRACT (R4, carried forward): ref=np is numpy fp32. numpy's
// c_einsum SOP remainder loop contracts to an ascending scalar FMA chain:
//   dot = fma(b,cb, fma(g,cg, rn(r*cr)))     <- acc=0, ascending
// np.sum(pix*pix) / np.sum(pal*pal) are separate ufunc passes (no FMA),
// pairwise base case n<8 = forward:
//   pp = ((r*r + g*g) + b*b),  cc = ((cr*cr + cg*cg) + cb*cb)
// d = (pp - 2*dot) + cc  left-to-right; argmin first-index strict <.
//
// R5 TRANSFORM (bit-exact, verified absmax=0): per-color (-2cr,-2cg,-2cb)
// precompute; RNE commutes with exact *(-2) (no denormals possible), so
//   fma(b,-2cb, fma(g,-2cg, rn(r*(-2cr)))) == -2*dot  bit-exactly and
//   d = rn(rn(pp + nd2) + cc) == rn(rn(pp - 2*dot) + cc).
//
// R6 TRANSFORM (bit-exact): packed FP32 (v_pk_fma_f32/v_pk_mul_f32/
// v_pk_add_f32, gfx90a+ VOP3P). Pixels (0,1) and (2,3) are paired into
// v2f registers (already adjacent VGPRs from the float4 loads); the 5
// distance ops per pixel-color become 5 packed ops per 2 pixels. Packed ops
// are IEEE RNE per element => bit-identical. argmin cmp/cndmask stay scalar
// (no packed f32 compare). 16 -> 11 VALU instrs per 2 pixels per color.
// File-scope `#pragma clang fp contract(off)` pins vector mul/add against
// hipcc's default contraction; dot chains use explicit elementwise fma.

#pragma clang fp contract(off)

typedef float v2f __attribute__((ext_vector_type(2)));

constexpr int HW   = 512 * 512;   // pixels per plane (2^18)
constexpr int NCOL = 64;

static __device__ __forceinline__ v2f splat2(float s) {
  v2f v; v.x = s; v.y = s; return v;
}

__global__ __launch_bounds__(256)
void color_reduce_kernel(const float* __restrict__ x,
                         const float* __restrict__ pal,
                         float* __restrict__ out,
                         int npix4) {
  __shared__ float4 coefN[NCOL];  // (-2cr, -2cg, -2cb, cc)
  __shared__ float4 palf[NCOL];   // (cr, cg, cb, --) original colors for output
  const int tid = threadIdx.x;
  if (tid < NCOL) {
    const float cr = pal[tid * 3 + 0];
    const float cg = pal[tid * 3 + 1];
    const float cb = pal[tid * 3 + 2];
    const float cc = __fadd_rn(__fadd_rn(__fmul_rn(cr, cr), __fmul_rn(cg, cg)),
                               __fmul_rn(cb, cb));
    coefN[tid] = make_float4(__fmul_rn(-2.0f, cr),
                             __fmul_rn(-2.0f, cg),
                             __fmul_rn(-2.0f, cb), cc);
    palf[tid] = make_float4(cr, cg, cb, 0.0f);
  }
  __syncthreads();

  const int i4 = blockIdx.x * blockDim.x + tid;   // group of 4 consecutive pixels
  if (i4 >= npix4) return;
  const int pix = i4 << 2;
  const int b   = pix >> 18;        // / HW
  const int j   = pix & (HW - 1);   // % HW
  const size_t base = (size_t)b * (3 * HW) + j;

  const float4 R  = *(const float4*)(x + base);
  const float4 G  = *(const float4*)(x + base + HW);
  const float4 Bl = *(const float4*)(x + base + 2 * HW);

  v2f r01, r23, g01, g23, b01, b23;
  r01.x = R.x;  r01.y = R.y;  r23.x = R.z;  r23.y = R.w;
  g01.x = G.x;  g01.y = G.y;  g23.x = G.z;  g23.y = G.w;
  b01.x = Bl.x; b01.y = Bl.y; b23.x = Bl.z; b23.y = Bl.w;

  // pp = rn(rn(rn(r*r) + rn(g*g)) + rn(b*b))  -- contract(off) pins each op
  const v2f pp01 = (r01 * r01 + g01 * g01) + b01 * b01;
  const v2f pp23 = (r23 * r23 + g23 * g23) + b23 * b23;

  v2f m01, m23;
  m01.x = 3.4e38f; m01.y = 3.4e38f;
  m23.x = 3.4e38f; m23.y = 3.4e38f;
  int idx0 = 0, idx1 = 0, idx2 = 0, idx3 = 0;

  // Full unroll: k is an inline constant in the idx cndmask.
#pragma unroll
  for (int k = 0; k < NCOL; ++k) {
    const float4 cf = coefN[k];
    const v2f cx = splat2(cf.x), cy = splat2(cf.y),
              cz = splat2(cf.z), cw = splat2(cf.w);

    // nd2 = fma(b,-2cb, fma(g,-2cg, rn(r*(-2cr)))) == -2*dot  (packed, RNE)
    const v2f nd2_01 = __builtin_elementwise_fma(b01, cz,
                         __builtin_elementwise_fma(g01, cy, r01 * cx));
    const v2f nd2_23 = __builtin_elementwise_fma(b23, cz,
                         __builtin_elementwise_fma(g23, cy, r23 * cx));
    const v2f d01 = (pp01 + nd2_01) + cw;
    const v2f d23 = (pp23 + nd2_23) + cw;

    // strict < => first-index tie-break (scalar cmp/cndmask per pixel)
    const bool l0 = d01.x < m01.x;
    const bool l1 = d01.y < m01.y;
    const bool l2 = d23.x < m23.x;
    const bool l3 = d23.y < m23.y;
    m01.x = l0 ? d01.x : m01.x;  idx0 = l0 ? k : idx0;
    m01.y = l1 ? d01.y : m01.y;  idx1 = l1 ? k : idx1;
    m23.x = l2 ? d23.x : m23.x;  idx2 = l2 ? k : idx2;
    m23.y = l3 ? d23.y : m23.y;  idx3 = l3 ? k : idx3;
  }

  const float4 c0 = palf[idx0], c1 = palf[idx1],
               c2 = palf[idx2], c3 = palf[idx3];
  *(float4*)(out + base)          = make_float4(c0.x, c1.x, c2.x, c3.x);
  *(float4*)(out + base + HW)     = make_float4(c0.y, c1.y, c2.y, c3.y);
  *(float4*)(out + base + 2 * HW) = make_float4(c0.z, c1.z, c2.z, c3.z);
}

extern "C" void kernel_launch(void* const* d_in, const int* in_sizes, int n_in,
                              void* d_out, int out_size, void* d_ws, size_t ws_size,
                              hipStream_t stream) {
  const float* x   = (const float*)d_in[0];
  const float* pal = (const float*)d_in[1];
  float* out = (float*)d_out;

  const int npix  = in_sizes[0] / 3;   // B*H*W = 2,097,152
  const int npix4 = npix / 4;          // 524,288 threads
  const int block = 256;
  const int grid  = (npix4 + block - 1) / block;
  hipLaunchKernelGGL(color_reduce_kernel, dim3(grid), dim3(block), 0, stream,
                     x, pal, out, npix4);
}